// Round 1
// baseline (258.910 us; speedup 1.0000x reference)
//
#include <hip/hip_runtime.h>
#include <math.h>

#define D 256
#define SEGS 64
#define RPB 512      // rows per block
#define THREADS 256  // 4 waves; each wave handles RPB/4 = 128 contiguous rows

// ---- ordered-uint encoding for float atomicMax ----
// key(f) is monotone in f; key >= 0x007FFFFF for all non-NaN floats,
// so a zero-initialized key acts as -inf identity.
__device__ __forceinline__ unsigned enc_f32(float f) {
  unsigned u = __float_as_uint(f);
  return (u & 0x80000000u) ? ~u : (u | 0x80000000u);
}
__device__ __forceinline__ float dec_f32(unsigned k) {
  unsigned u = (k & 0x80000000u) ? (k ^ 0x80000000u) : ~k;
  return __uint_as_float(u);
}

// Detect index element width. Indices are sorted in [0,64); the last int32
// word is 63 (a.s.) if data is int32, but is the high word (0) of an int64
// if data is int64. stride: 1 => int32, 2 => int64 (read low words).
__global__ void detect_kernel(const int* __restrict__ idx, int n, int* flag) {
  if (blockIdx.x == 0 && threadIdx.x == 0)
    *flag = (idx[(size_t)n - 1] == 0) ? 2 : 1;
}

__global__ void hist_kernel(const int* __restrict__ idx, int n,
                            const int* __restrict__ flag,
                            int* __restrict__ counts) {
  __shared__ int h[SEGS];
  if (threadIdx.x < SEGS) h[threadIdx.x] = 0;
  __syncthreads();
  const int stride = *flag;
  int gid = blockIdx.x * blockDim.x + threadIdx.x;
  int gsz = gridDim.x * blockDim.x;
  for (int i = gid; i < n; i += gsz) {
    int s = idx[(size_t)i * stride];
    atomicAdd(&h[s & (SEGS - 1)], 1);
  }
  __syncthreads();
  if (threadIdx.x < SEGS) atomicAdd(&counts[threadIdx.x], h[threadIdx.x]);
}

__global__ __launch_bounds__(THREADS, 8)
void agg_kernel(const float* __restrict__ feat, const int* __restrict__ idx,
                const int* __restrict__ flag, float* __restrict__ sums,
                unsigned* __restrict__ maxk, int n) {
  __shared__ int s_idx[RPB];
  const int stride = *flag;
  const int r0 = blockIdx.x * RPB;
  const int rows = min(RPB, n - r0);

  for (int i = threadIdx.x; i < rows; i += THREADS)
    s_idx[i] = idx[(size_t)(r0 + i) * stride];
  __syncthreads();

  const int lane = threadIdx.x & 63;
  const int wave = threadIdx.x >> 6;
  const int rb = wave * (RPB / 4);
  const int re = min(rb + (RPB / 4), rows);
  if (rb >= rows) return;

  float4 sum = make_float4(0.f, 0.f, 0.f, 0.f);
  float4 mx  = make_float4(-INFINITY, -INFINITY, -INFINITY, -INFINITY);
  int cur = s_idx[rb];

  const float* base = feat + (size_t)r0 * D + lane * 4;

  for (int i = rb; i < re; ++i) {
    int s = s_idx[i];  // wave-uniform broadcast read
    if (s != cur) {    // wave-uniform, rare (<=63 boundaries total)
      float* sp = sums + cur * D + lane * 4;
      atomicAdd(sp + 0, sum.x); atomicAdd(sp + 1, sum.y);
      atomicAdd(sp + 2, sum.z); atomicAdd(sp + 3, sum.w);
      unsigned* mp = maxk + cur * D + lane * 4;
      atomicMax(mp + 0, enc_f32(mx.x)); atomicMax(mp + 1, enc_f32(mx.y));
      atomicMax(mp + 2, enc_f32(mx.z)); atomicMax(mp + 3, enc_f32(mx.w));
      sum = make_float4(0.f, 0.f, 0.f, 0.f);
      mx  = make_float4(-INFINITY, -INFINITY, -INFINITY, -INFINITY);
      cur = s;
    }
    const float4 v = *reinterpret_cast<const float4*>(base + (size_t)i * D);
    sum.x += v.x; sum.y += v.y; sum.z += v.z; sum.w += v.w;
    mx.x = fmaxf(mx.x, v.x); mx.y = fmaxf(mx.y, v.y);
    mx.z = fmaxf(mx.z, v.z); mx.w = fmaxf(mx.w, v.w);
  }

  // final flush
  float* sp = sums + cur * D + lane * 4;
  atomicAdd(sp + 0, sum.x); atomicAdd(sp + 1, sum.y);
  atomicAdd(sp + 2, sum.z); atomicAdd(sp + 3, sum.w);
  unsigned* mp = maxk + cur * D + lane * 4;
  atomicMax(mp + 0, enc_f32(mx.x)); atomicMax(mp + 1, enc_f32(mx.y));
  atomicMax(mp + 2, enc_f32(mx.z)); atomicMax(mp + 3, enc_f32(mx.w));
}

__global__ void finalize_kernel(const float* __restrict__ sums,
                                const unsigned* __restrict__ maxk,
                                const int* __restrict__ counts,
                                float* __restrict__ out) {
  int i = blockIdx.x * blockDim.x + threadIdx.x;
  if (i >= SEGS * 2 * D) return;
  int s = i / (2 * D);
  int j = i % (2 * D);
  int c = counts[s];
  float v;
  if (j < D)
    v = (c > 0) ? sums[s * D + j] / (float)c : 0.0f;
  else
    v = (c > 0) ? dec_f32(maxk[s * D + (j - D)]) : 0.0f;
  out[i] = v;
}

extern "C" void kernel_launch(void* const* d_in, const int* in_sizes, int n_in,
                              void* d_out, int out_size, void* d_ws, size_t ws_size,
                              hipStream_t stream) {
  const float* feat = (const float*)d_in[0];
  const int*   idx  = (const int*)d_in[1];
  const int n = in_sizes[1];
  float* out = (float*)d_out;

  char* ws = (char*)d_ws;
  float*    sums   = (float*)ws;                          // 64*256*4 = 64 KiB
  unsigned* maxk   = (unsigned*)(ws + SEGS * D * 4);      // 64 KiB
  int*      counts = (int*)(ws + 2 * SEGS * D * 4);       // 256 B
  int*      flag   = counts + SEGS;                       // 4 B

  const size_t zero_bytes = 2 * (size_t)SEGS * D * 4 + SEGS * 4;
  hipMemsetAsync(ws, 0, zero_bytes, stream);

  detect_kernel<<<1, 64, 0, stream>>>(idx, n, flag);
  hist_kernel<<<512, 256, 0, stream>>>(idx, n, flag, counts);

  const int nblocks = (n + RPB - 1) / RPB;
  agg_kernel<<<nblocks, THREADS, 0, stream>>>(feat, idx, flag, sums, maxk, n);

  finalize_kernel<<<(SEGS * 2 * D + 255) / 256, 256, 0, stream>>>(
      sums, maxk, counts, out);
}

// Round 2
// 217.848 us; speedup vs baseline: 1.1885x; 1.1885x over previous
//
#include <hip/hip_runtime.h>
#include <math.h>

#define D 256
#define SEGS 64
#define RPB 512      // rows per block
#define THREADS 256  // 4 waves; each wave handles RPB/4 = 128 contiguous rows

typedef float f32x4 __attribute__((ext_vector_type(4)));

// ---- ordered-uint encoding for float atomicMax ----
// key(f) is monotone in f; key >= 0x007FFFFF for all non-NaN floats,
// so a zero-initialized key acts as -inf identity.
__device__ __forceinline__ unsigned enc_f32(float f) {
  unsigned u = __float_as_uint(f);
  return (u & 0x80000000u) ? ~u : (u | 0x80000000u);
}
__device__ __forceinline__ float dec_f32(unsigned k) {
  unsigned u = (k & 0x80000000u) ? (k ^ 0x80000000u) : ~k;
  return __uint_as_float(u);
}

// Index width detection (int32 vs int64 stored little-endian):
// indices are sorted in [0,64); last int32 word is 63 if int32 data,
// but is the high word (0) of the last int64 element if int64 data.
__device__ __forceinline__ int idx_stride(const int* idx, int n) {
  return (idx[(size_t)n - 1] == 0) ? 2 : 1;
}

__global__ __launch_bounds__(THREADS, 8)
void agg_kernel(const float* __restrict__ feat, const int* __restrict__ idx,
                float* __restrict__ sums, unsigned* __restrict__ maxk,
                int* __restrict__ counts, int n) {
  __shared__ int s_idx[RPB];
  const int stride = idx_stride(idx, n);
  const int r0 = blockIdx.x * RPB;
  const int rows = min(RPB, n - r0);

  for (int i = threadIdx.x; i < rows; i += THREADS)
    s_idx[i] = idx[(size_t)(r0 + i) * stride];
  __syncthreads();

  const int lane = threadIdx.x & 63;
  const int wave = threadIdx.x >> 6;
  int i = wave * (RPB / 4);
  const int re = min(i + (RPB / 4), rows);
  if (i >= re) return;

  const float* base = feat + (size_t)r0 * D + lane * 4;
  const int last = s_idx[re - 1];

  while (i < re) {
    const int cur = s_idx[i];
    int j;
    if (cur == last) {
      j = re;                     // fast path: single run to range end (common)
    } else {
      j = i + 1;                  // rare: <=63 boundary waves in whole grid
      while (s_idx[j] == cur) ++j;  // bounded: s_idx[re-1] != cur
    }

    f32x4 sum = {0.f, 0.f, 0.f, 0.f};
    f32x4 mx  = {-INFINITY, -INFINITY, -INFINITY, -INFINITY};
#pragma unroll 4
    for (int k = i; k < j; ++k) {
      const f32x4 v = __builtin_nontemporal_load(
          reinterpret_cast<const f32x4*>(base + (size_t)k * D));
      sum += v;
      mx.x = __builtin_fmaxf(mx.x, v.x);
      mx.y = __builtin_fmaxf(mx.y, v.y);
      mx.z = __builtin_fmaxf(mx.z, v.z);
      mx.w = __builtin_fmaxf(mx.w, v.w);
    }

    float* sp = sums + cur * D + lane * 4;
    atomicAdd(sp + 0, sum.x); atomicAdd(sp + 1, sum.y);
    atomicAdd(sp + 2, sum.z); atomicAdd(sp + 3, sum.w);
    unsigned* mp = maxk + cur * D + lane * 4;
    atomicMax(mp + 0, enc_f32(mx.x)); atomicMax(mp + 1, enc_f32(mx.y));
    atomicMax(mp + 2, enc_f32(mx.z)); atomicMax(mp + 3, enc_f32(mx.w));
    if (lane == 0) atomicAdd(&counts[cur], j - i);

    i = j;
  }
}

__global__ void finalize_kernel(const float* __restrict__ sums,
                                const unsigned* __restrict__ maxk,
                                const int* __restrict__ counts,
                                float* __restrict__ out) {
  int i = blockIdx.x * blockDim.x + threadIdx.x;
  if (i >= SEGS * 2 * D) return;
  int s = i / (2 * D);
  int j = i % (2 * D);
  int c = counts[s];
  float v;
  if (j < D)
    v = (c > 0) ? sums[s * D + j] / (float)c : 0.0f;
  else
    v = (c > 0) ? dec_f32(maxk[s * D + (j - D)]) : 0.0f;
  out[i] = v;
}

extern "C" void kernel_launch(void* const* d_in, const int* in_sizes, int n_in,
                              void* d_out, int out_size, void* d_ws, size_t ws_size,
                              hipStream_t stream) {
  const float* feat = (const float*)d_in[0];
  const int*   idx  = (const int*)d_in[1];
  const int n = in_sizes[1];
  float* out = (float*)d_out;

  char* ws = (char*)d_ws;
  float*    sums   = (float*)ws;                          // 64 KiB
  unsigned* maxk   = (unsigned*)(ws + SEGS * D * 4);      // 64 KiB
  int*      counts = (int*)(ws + 2 * SEGS * D * 4);       // 256 B

  const size_t zero_bytes = 2 * (size_t)SEGS * D * 4 + SEGS * 4;
  hipMemsetAsync(ws, 0, zero_bytes, stream);

  const int nblocks = (n + RPB - 1) / RPB;
  agg_kernel<<<nblocks, THREADS, 0, stream>>>(feat, idx, sums, maxk, counts, n);

  finalize_kernel<<<(SEGS * 2 * D + 255) / 256, 256, 0, stream>>>(
      sums, maxk, counts, out);
}

// Round 3
// 217.703 us; speedup vs baseline: 1.1893x; 1.0007x over previous
//
#include <hip/hip_runtime.h>
#include <math.h>

#define D 256
#define SEGS 64
#define RPB 512      // rows per block
#define THREADS 256  // 4 waves; each wave streams RPB/4 = 128 contiguous rows

typedef float f32x4 __attribute__((ext_vector_type(4)));

// ---- ordered-uint encoding for float atomicMax ----
// key(f) monotone in f; key >= 0x007FFFFF for all finite floats,
// so the zero-initialized key acts as a -inf identity.
__device__ __forceinline__ unsigned enc_f32(float f) {
  unsigned u = __float_as_uint(f);
  return (u & 0x80000000u) ? ~u : (u | 0x80000000u);
}
__device__ __forceinline__ float dec_f32(unsigned k) {
  unsigned u = (k & 0x80000000u) ? (k ^ 0x80000000u) : ~k;
  return __uint_as_float(u);
}

// init: block s zeros segment s's ws slice and binary-searches bounds[s+1] =
// lower_bound(idx, s+1). idx width (int32 vs int64) detected from the last
// int32 word: sorted data ends in 63 (int32) or the 0 high-word (int64).
__global__ void init_kernel(const int* __restrict__ idx, int n,
                            float* __restrict__ sums,
                            unsigned* __restrict__ maxk,
                            int* __restrict__ bounds) {
  const int s = blockIdx.x;
  if (threadIdx.x < D) {
    sums[s * D + threadIdx.x] = 0.0f;
    maxk[s * D + threadIdx.x] = 0u;
  }
  if (threadIdx.x == 0) {
    const int stride = (idx[(size_t)n - 1] == 0) ? 2 : 1;
    const int v = s + 1;
    int lo = 0, hi = n;
    while (lo < hi) {
      int mid = (lo + hi) >> 1;
      if (idx[(size_t)mid * stride] < v) lo = mid + 1; else hi = mid;
    }
    bounds[s + 1] = lo;
    if (s == 0) bounds[0] = 0;
  }
}

__global__ __launch_bounds__(THREADS, 4)
void agg_kernel(const float* __restrict__ feat, const int* __restrict__ bounds,
                float* __restrict__ sums, unsigned* __restrict__ maxk, int n) {
  const int lane = threadIdx.x & 63;
  const int wave = threadIdx.x >> 6;
  int i = blockIdx.x * RPB + wave * (RPB / 4);
  const int re = min(i + (RPB / 4), n);
  if (i >= re) return;

  // b_end = bounds[lane+1] = end row of segment `lane` (one coalesced load).
  const int b_end = bounds[lane + 1];
  // segment of row i: number of segment-ends <= i (handles empties).
  int cur = (int)__popcll(__ballot(b_end <= i));

  const float* base = feat + lane * 4;

  while (true) {
    const int e = __shfl(b_end, cur);   // end of current segment
    const int j = min(re, e);           // invariant: j > i

    f32x4 sum = {0.f, 0.f, 0.f, 0.f};
    f32x4 mx  = {-INFINITY, -INFINITY, -INFINITY, -INFINITY};
#pragma unroll 8
    for (int k = i; k < j; ++k) {
      const f32x4 v = __builtin_nontemporal_load(
          reinterpret_cast<const f32x4*>(base + (size_t)k * D));
      sum += v;
      mx.x = __builtin_fmaxf(mx.x, v.x);
      mx.y = __builtin_fmaxf(mx.y, v.y);
      mx.z = __builtin_fmaxf(mx.z, v.z);
      mx.w = __builtin_fmaxf(mx.w, v.w);
    }

    float* sp = sums + cur * D + lane * 4;
    atomicAdd(sp + 0, sum.x); atomicAdd(sp + 1, sum.y);
    atomicAdd(sp + 2, sum.z); atomicAdd(sp + 3, sum.w);
    unsigned* mp = maxk + cur * D + lane * 4;
    atomicMax(mp + 0, enc_f32(mx.x)); atomicMax(mp + 1, enc_f32(mx.y));
    atomicMax(mp + 2, enc_f32(mx.z)); atomicMax(mp + 3, enc_f32(mx.w));

    if (j >= re) break;
    i = j;
    do { ++cur; } while (__shfl(b_end, cur) <= i);  // skip empty segments
  }
}

__global__ void finalize_kernel(const float* __restrict__ sums,
                                const unsigned* __restrict__ maxk,
                                const int* __restrict__ bounds,
                                float* __restrict__ out) {
  int t = blockIdx.x * blockDim.x + threadIdx.x;
  if (t >= SEGS * 2 * D) return;
  int s = t / (2 * D);
  int j = t % (2 * D);
  int c = bounds[s + 1] - bounds[s];
  float v;
  if (j < D)
    v = (c > 0) ? sums[s * D + j] / (float)c : 0.0f;
  else
    v = (c > 0) ? dec_f32(maxk[s * D + (j - D)]) : 0.0f;
  out[t] = v;
}

extern "C" void kernel_launch(void* const* d_in, const int* in_sizes, int n_in,
                              void* d_out, int out_size, void* d_ws, size_t ws_size,
                              hipStream_t stream) {
  const float* feat = (const float*)d_in[0];
  const int*   idx  = (const int*)d_in[1];
  const int n = in_sizes[1];
  float* out = (float*)d_out;

  char* ws = (char*)d_ws;
  float*    sums   = (float*)ws;                       // 64 KiB
  unsigned* maxk   = (unsigned*)(ws + SEGS * D * 4);   // 64 KiB
  int*      bounds = (int*)(ws + 2 * SEGS * D * 4);    // 65 ints

  init_kernel<<<SEGS, THREADS, 0, stream>>>(idx, n, sums, maxk, bounds);

  const int nblocks = (n + RPB - 1) / RPB;
  agg_kernel<<<nblocks, THREADS, 0, stream>>>(feat, bounds, sums, maxk, n);

  finalize_kernel<<<(SEGS * 2 * D + THREADS - 1) / THREADS, THREADS, 0, stream>>>(
      sums, maxk, bounds, out);
}